// Round 2
// baseline (205.543 us; speedup 1.0000x reference)
//
#include <hip/hip_runtime.h>

#define SCALE 0.17677669529663687f  // 1/sqrt(32)

// ---------------------------------------------------------------------------
// One block per query row i. 512 blocks x 1024 thr (16 waves), target 2
// blocks/CU (32 waves = 100% occupancy), VGPR cap 64 (no spill).
//
// Prologue: q_s = (x[i]@Wq)*SCALE;
//   s_qc[c*16+h]   = sum_d q_s[h*32+d]*We[c*256+h*32+d]   (e-coef)
//   s_qc[c*16+8+h] = sum_d q_s[h*32+d]*Wk[c*256+h*32+d]   (x-coef)
// P1: thread = (j = t&511, cpart = t>>9). acc[8] = partial logits over 32 c.
//     Upper half parks partials in s_pt (dead there); lower half combines.
//     Each e element read exactly once.
// P2 (waves 0-7 only): in-register softmax; butterfly max/sum per head;
//     write UNNORMALIZED probs transposed s_pt[j][h]; 1/sum -> s_inv.
// P3 (all 16 waves): lane=c, wave owns 32 j; ae/px partials -> LDS atomicAdd.
// Normalize by s_inv, then epilogue GEMMs (scratch aliased into s_pt).
// ---------------------------------------------------------------------------
__global__ __launch_bounds__(1024, 2) void fused_kernel(
    const float* __restrict__ e, const float* __restrict__ x,
    const float* __restrict__ Wq, const float* __restrict__ Wk,
    const float* __restrict__ We, const float* __restrict__ Wv,
    const float* __restrict__ Wo, const float* __restrict__ bo,
    float* __restrict__ out) {
  const int t = threadIdx.x, i = blockIdx.x;
  const int lane = t & 63, w = t >> 6;   // wave 0..15
  const int j = t & 511;                 // phase-1 row index
  const int cpart = t >> 9;              // phase-1 c-half: 0 or 1

  __shared__ float s_x[64];
  __shared__ __align__(16) float s_q[256];
  __shared__ __align__(16) float s_qc[1024];   //  4 KB coefs
  __shared__ __align__(16) float s_pt[4096];   // 16 KB: P1 partials -> probs -> epi scratch
  __shared__ __align__(16) float s_red[64];    // per-wave max partials  [w][h]
  __shared__ __align__(16) float s_red2[64];   // per-wave sum partials  [w][h]
  __shared__ float s_inv[8];
  __shared__ __align__(16) float s_ae[512];
  __shared__ __align__(16) float s_px[512];

  // ---- init + prologue
  if (t < 512) { s_ae[t] = 0.f; s_px[t] = 0.f; }
  if (t < 64) s_x[t] = x[i * 64 + t];
  __syncthreads();
  if (t < 256) {
    float a = 0;
#pragma unroll 8
    for (int c = 0; c < 64; ++c) a += s_x[c] * Wq[c * 256 + t];
    s_q[t] = a * SCALE;
  }
  __syncthreads();
  {  // coefficients: 1024 threads = 64 c x {We,Wk} x 8 h
    const int c = t >> 4, hv = t & 15, which = hv >> 3, h = hv & 7;
    const float* W = which ? Wk : We;
    const float4* wr = (const float4*)(W + c * 256 + h * 32);
    const float4* qr = (const float4*)(s_q + h * 32);
    float s = 0;
#pragma unroll
    for (int u = 0; u < 8; ++u) {
      float4 wv4 = wr[u], qv = qr[u];
      s += qv.x * wv4.x + qv.y * wv4.y + qv.z * wv4.z + qv.w * wv4.w;
    }
    s_qc[c * 16 + which * 8 + h] = s;
  }
  __syncthreads();

  // ---- Phase 1: partial logits for row j over this thread's 32 channels
  float acc[8];
  {
    const float4* erow = (const float4*)(e + (size_t)(i * 512 + j) * 64 + cpart * 32);
    const float4* xrow = (const float4*)(x + j * 64 + cpart * 32);
#pragma unroll
    for (int h = 0; h < 8; ++h) acc[h] = 0.f;
#pragma unroll 4
    for (int c4 = 0; c4 < 8; ++c4) {
      float4 E = erow[c4];
      float4 X = xrow[c4];
      const float* qc = s_qc + (cpart * 8 + c4) * 64;  // wave-uniform LDS broadcast
#pragma unroll
      for (int h = 0; h < 8; ++h) {
        acc[h] += E.x * qc[h]      + E.y * qc[16 + h]
                + E.z * qc[32 + h] + E.w * qc[48 + h]
                + X.x * qc[8 + h]  + X.y * qc[24 + h]
                + X.z * qc[40 + h] + X.w * qc[56 + h];
      }
    }
  }
  // upper c-half parks its partials in s_pt (dead until probs are written)
  if (cpart) {
    *(float4*)(s_pt + j * 8)     = make_float4(acc[0], acc[1], acc[2], acc[3]);
    *(float4*)(s_pt + j * 8 + 4) = make_float4(acc[4], acc[5], acc[6], acc[7]);
  }
  __syncthreads();

  // ---- Phase 2: softmax on waves 0-7 (thread j holds full logits[8])
  if (!cpart) {
    float4 a0 = ((const float4*)(s_pt + j * 8))[0];
    float4 a1 = ((const float4*)(s_pt + j * 8))[1];
    acc[0] += a0.x; acc[1] += a0.y; acc[2] += a0.z; acc[3] += a0.w;
    acc[4] += a1.x; acc[5] += a1.y; acc[6] += a1.z; acc[7] += a1.w;
#pragma unroll
    for (int h = 0; h < 8; ++h) {
      float m = acc[h];
#pragma unroll
      for (int off = 32; off; off >>= 1) m = fmaxf(m, __shfl_xor(m, off, 64));
      if (lane == 0) s_red[w * 8 + h] = m;
    }
  }
  __syncthreads();
  if (!cpart) {
    // global max per head (uniform LDS broadcast)
    float4 M0 = ((const float4*)s_red)[0], M1 = ((const float4*)s_red)[1];
#pragma unroll
    for (int ww = 1; ww < 8; ++ww) {
      float4 a = ((const float4*)s_red)[ww * 2], b = ((const float4*)s_red)[ww * 2 + 1];
      M0.x = fmaxf(M0.x, a.x); M0.y = fmaxf(M0.y, a.y);
      M0.z = fmaxf(M0.z, a.z); M0.w = fmaxf(M0.w, a.w);
      M1.x = fmaxf(M1.x, b.x); M1.y = fmaxf(M1.y, b.y);
      M1.z = fmaxf(M1.z, b.z); M1.w = fmaxf(M1.w, b.w);
    }
    acc[0] = __expf(acc[0] - M0.x); acc[1] = __expf(acc[1] - M0.y);
    acc[2] = __expf(acc[2] - M0.z); acc[3] = __expf(acc[3] - M0.w);
    acc[4] = __expf(acc[4] - M1.x); acc[5] = __expf(acc[5] - M1.y);
    acc[6] = __expf(acc[6] - M1.z); acc[7] = __expf(acc[7] - M1.w);
    *(float4*)(s_pt + j * 8)     = make_float4(acc[0], acc[1], acc[2], acc[3]);
    *(float4*)(s_pt + j * 8 + 4) = make_float4(acc[4], acc[5], acc[6], acc[7]);
#pragma unroll
    for (int h = 0; h < 8; ++h) {
      float s = acc[h];
#pragma unroll
      for (int off = 32; off; off >>= 1) s += __shfl_xor(s, off, 64);
      if (lane == 0) s_red2[w * 8 + h] = s;
    }
  }
  __syncthreads();
  if (t < 8) {  // 1/denominator per head (read after next barrier)
    float s = 0;
#pragma unroll
    for (int ww = 0; ww < 8; ++ww) s += s_red2[ww * 8 + t];
    s_inv[t] = 1.0f / s;
  }

  // ---- Phase 3: lane=c, wave w owns j in [w*32, w*32+32)
  {
    float ae[8], px[8];
#pragma unroll
    for (int h = 0; h < 8; ++h) { ae[h] = 0.f; px[h] = 0.f; }
    const float* ep = e + (size_t)i * 32768 + w * 2048 + lane;
    const float* xp = x + w * 2048 + lane;
#pragma unroll 4
    for (int jj = 0; jj < 32; ++jj) {
      float ev = ep[jj * 64];  // coalesced 256B/wave
      float xv = xp[jj * 64];
      const float4* pt = (const float4*)(s_pt + (w * 32 + jj) * 8);  // uniform broadcast
      float4 p0 = pt[0], p1 = pt[1];
      ae[0] += p0.x * ev; ae[1] += p0.y * ev; ae[2] += p0.z * ev; ae[3] += p0.w * ev;
      ae[4] += p1.x * ev; ae[5] += p1.y * ev; ae[6] += p1.z * ev; ae[7] += p1.w * ev;
      px[0] += p0.x * xv; px[1] += p0.y * xv; px[2] += p0.z * xv; px[3] += p0.w * xv;
      px[4] += p1.x * xv; px[5] += p1.y * xv; px[6] += p1.z * xv; px[7] += p1.w * xv;
    }
#pragma unroll
    for (int h = 0; h < 8; ++h) {
      atomicAdd(&s_ae[h * 64 + lane], ae[h]);  // ds_add_f32, addresses disjoint in-wave
      atomicAdd(&s_px[h * 64 + lane], px[h]);
    }
  }
  __syncthreads();

  // ---- fold in softmax normalization
  if (t < 512) {
    s_ae[t] *= s_inv[t >> 6];
  } else {
    const int t2 = t - 512;
    s_px[t2] *= s_inv[t2 >> 6];
  }
  __syncthreads();

  // ---- Epilogue (scratch aliases the now-dead s_pt)
  float* s_eb  = s_pt;         // 1024 floats: partial emb
  float* s_emb = s_pt + 1024;  // 256 floats
  float* s_op  = s_pt + 1280;  // 1024 floats
  {
    const int nd = t & 255, ch = t >> 8, hn = nd >> 5;
    float emb = 0;
    const int cb = ch * 16;
#pragma unroll
    for (int c = cb; c < cb + 16; ++c)
      emb += s_ae[hn * 64 + c] * We[c * 256 + nd] + s_px[hn * 64 + c] * Wv[c * 256 + nd];
    s_eb[ch * 256 + nd] = emb;
  }
  __syncthreads();
  if (t < 256) s_emb[t] = s_eb[t] + s_eb[256 + t] + s_eb[512 + t] + s_eb[768 + t];
  __syncthreads();
  {
    const int o = t & 63, mc = t >> 6;
    float oo = 0;
#pragma unroll
    for (int m2 = mc * 16; m2 < mc * 16 + 16; ++m2) oo += s_emb[m2] * Wo[m2 * 64 + o];
    s_op[mc * 64 + o] = oo;
  }
  __syncthreads();
  if (t < 64) {
    float r = bo[t];
#pragma unroll
    for (int w2 = 0; w2 < 16; ++w2) r += s_op[w2 * 64 + t];
    out[i * 64 + t] = r;
  }
}

extern "C" void kernel_launch(void* const* d_in, const int* in_sizes, int n_in,
                              void* d_out, int out_size, void* d_ws, size_t ws_size,
                              hipStream_t stream) {
  const float* x  = (const float*)d_in[0];
  const float* e  = (const float*)d_in[1];
  const float* Wq = (const float*)d_in[2];
  const float* Wk = (const float*)d_in[3];
  const float* Wv = (const float*)d_in[4];
  const float* We = (const float*)d_in[5];
  const float* Wo = (const float*)d_in[6];
  const float* bo = (const float*)d_in[7];
  float* out = (float*)d_out;

  hipLaunchKernelGGL(fused_kernel, dim3(512), dim3(1024), 0, stream,
                     e, x, Wq, Wk, We, Wv, Wo, bo, out);
}